// Round 12
// baseline (117.069 us; speedup 1.0000x reference)
//
#include <hip/hip_runtime.h>

namespace {

constexpr int T_LEN = 512;
constexpr float LOG2E = 1.4426950408889634f;

typedef _Float16 half4 __attribute__((ext_vector_type(4)));
typedef _Float16 half2v __attribute__((ext_vector_type(2)));
typedef float v4f __attribute__((ext_vector_type(4)));

__device__ __forceinline__ float fexp2(float a) {
#if __has_builtin(__builtin_amdgcn_exp2f)
    return __builtin_amdgcn_exp2f(a);
#else
    return exp2f(a);
#endif
}

__device__ __forceinline__ v4f mfma16h(half4 a, half4 b, v4f c) {
#if __has_builtin(__builtin_amdgcn_mfma_f32_16x16x16f16)
    return __builtin_amdgcn_mfma_f32_16x16x16f16(a, b, c, 0, 0, 0);
#else
    v4f d;
    asm volatile("v_mfma_f32_16x16x16_f16 %0, %1, %2, %3\n\ts_nop 7\n\ts_nop 7"
                 : "=v"(d) : "v"(a), "v"(b), "v"(c));
    return d;
#endif
}

__device__ __forceinline__ unsigned pk_f16(float a, float b) {
#if __has_builtin(__builtin_amdgcn_cvt_pkrtz)
    return __builtin_bit_cast(unsigned, __builtin_amdgcn_cvt_pkrtz(a, b));
#else
    half2v r; r[0] = (_Float16)a; r[1] = (_Float16)b;
    return __builtin_bit_cast(unsigned, r);
#endif
}

// DPP mov, compile-time ctrl. ROW_ROR:N = 0x120|N rotates within 16-lane rows.
template<int CTRL>
__device__ __forceinline__ float dpp_mov_f(float v) {
    return __builtin_bit_cast(float,
        __builtin_amdgcn_mov_dpp(__builtin_bit_cast(int, v), CTRL, 0xF, 0xF, false));
}

// select d[q] with compile-time vector indices (q = qb1*2 + qb0, per-lane)
__device__ __forceinline__ float sel4(v4f d, bool qb0, bool qb1) {
    float a = qb0 ? d[1] : d[0];
    float b = qb0 ? d[3] : d[2];
    return qb1 ? b : a;
}

// one (row, element) gate evaluation + h update (identical math since R5)
__device__ __forceinline__ float gru_pair(float drp, float dzp, float dnp,
                                          float xt, float wihn, float bihn,
                                          float hp) {
    float Er = fexp2(drp);
    float Ez = fexp2(dzp);
    float pr = 1.0f + Er;
    float pz = 1.0f + Ez;
    float ip = __builtin_amdgcn_rcpf(pr * pz);
    float r  = ip * pz;                  // sigmoid(r-pre)
    float z  = ip * pr;                  // sigmoid(z-pre)
    float xn = __builtin_fmaf(xt, wihn, bihn);
    float v  = __builtin_fmaf(r, dnp, xn);
    float n  = __builtin_fmaf(-2.0f, __builtin_amdgcn_rcpf(1.0f + fexp2(v)), 1.0f);
    return __builtin_fmaf(z, hp - n, n); // (1-z)*n + z*h
}

__global__ __launch_bounds__(64) void gru_mfma4d(
        const float* __restrict__ x,
        const float* __restrict__ W_ih,
        const float* __restrict__ W_hh,
        const float* __restrict__ b_ih,
        const float* __restrict__ b_hh,
        const float* __restrict__ fc_w,
        const float* __restrict__ fc_b,
        float* __restrict__ out) {
    const int L  = threadIdx.x;      // 0..63
    const int e  = L & 15;           // MFMA column; cols with same (e&3) duplicate
    const int g  = L >> 4;           // row group; D rows jD..jD+3 of col e
    const int jD = g * 4;
    const int q    = (e >> 2) & 3;   // which D-reg (row jD+q) this lane gates
    const bool qb0 = (q & 1) != 0;
    const bool qb1 = (q & 2) != 0;
    const int ecol = e & 3;          // real batch column within the group
    const int be   = blockIdx.x * 4 + ecol;
    const int rme  = jD + q;         // the single gate row this lane owns

    // probe ROW_ROR:4 direction once: after ror4, does this lane hold lane e+4's
    // value (no flip) or lane e-4's (flip)? Wave-uniform.
    const int tprobe = __builtin_amdgcn_mov_dpp(e, 0x124, 0xF, 0xF, false);
    const bool flip = (((tprobe - e) & 15) != 4);

    const float sR = -LOG2E;         // sigmoid scaling folded into weights
    const float sN = 2.0f * LOG2E;   // tanh scaling

    // ---- A fragments: W_hh rows (gate out m = e; k = jD..jD+3), scaled, f16
    half4 ar_h, az_h, an_h;
#pragma unroll
    for (int i = 0; i < 4; ++i) {
        ar_h[i] = (_Float16)(W_hh[(0  + e) * 16 + jD + i] * sR);
        az_h[i] = (_Float16)(W_hh[(16 + e) * 16 + jD + i] * sR);
        an_h[i] = (_Float16)(W_hh[(32 + e) * 16 + jD + i] * sN);
    }

    // ---- loop-invariant MFMA C-operands: bias vectors (xt folded post-sel)
    v4f c_r, c_z, c_n;
#pragma unroll
    for (int i = 0; i < 4; ++i) {
        int rj = jD + i;
        c_r[i] = (b_ih[rj]      + b_hh[rj])      * sR;
        c_z[i] = (b_ih[16 + rj] + b_hh[16 + rj]) * sR;
        c_n[i] = b_hh[32 + rj] * sN;
    }
    // per-lane scalars for this lane's single gate row
    const float wihr_s = W_ih[rme]      * sR;
    const float wihz_s = W_ih[16 + rme] * sR;
    const float wihn_s = W_ih[32 + rme] * sN;
    const float bihn_s = b_ih[32 + rme] * sN;

    // ---- x timeline (duplicate lanes hit identical addresses; L1 broadcasts)
    const float4* xb = (const float4*)(x + (size_t)be * T_LEN);
    float4 xc0 = xb[0], xc1 = xb[1], xc2 = xb[2], xc3 = xb[3];

    float hp = 0.f;                      // this lane's h row (fp32 master)
    uint2 hz; hz.x = 0u; hz.y = 0u;
    half4 hf = __builtin_bit_cast(half4, hz);   // B-frag: rows jD..jD+3 (f16)

#pragma unroll 1
    for (int c = 0; c < T_LEN / 16; ++c) {
        float4 xn0, xn1, xn2, xn3;
        if (c + 1 < T_LEN / 16) {
            xn0 = xb[(c + 1) * 4 + 0];
            xn1 = xb[(c + 1) * 4 + 1];
            xn2 = xb[(c + 1) * 4 + 2];
            xn3 = xb[(c + 1) * 4 + 3];
        }
#pragma unroll
        for (int s = 0; s < 16; ++s) {
            float4 q4 = (s < 4) ? xc0 : (s < 8) ? xc1 : (s < 12) ? xc2 : xc3;
            float xt  = ((s & 3) == 0) ? q4.x : ((s & 3) == 1) ? q4.y
                      : ((s & 3) == 2) ? q4.z : q4.w;

            // matvec on MFMA pipe: ONE f16 MFMA per gate, bias in C
            v4f dr = mfma16h(ar_h, hf, c_r);
            v4f dz = mfma16h(az_h, hf, c_z);
            v4f dn = mfma16h(an_h, hf, c_n);

            // 4-way duplication split: this lane gates only D-reg q (row jD+q)
            float d_r = __builtin_fmaf(xt, wihr_s, sel4(dr, qb0, qb1));
            float d_z = __builtin_fmaf(xt, wihz_s, sel4(dz, qb0, qb1));
            float d_n = sel4(dn, qb0, qb1);
            float hn = gru_pair(d_r, d_z, d_n, xt, wihn_s, bihn_s, hp);
            hp = hn;

            // reassemble B-frag via 3 DPP row-rotations (all partners ±{4,8,12})
            float v0 = hn;
            float v1 = dpp_mov_f<0x124>(hn);   // ror:4
            float v2 = dpp_mov_f<0x128>(hn);   // ror:8 (xor-8, dir-independent)
            float v3 = dpp_mov_f<0x12C>(hn);   // ror:12
            // normalize direction so v_k = row (q+k)&3
            float t1 = flip ? v3 : v1;
            float t3 = flip ? v1 : v3;
            // row m <- v_{(m-q)&3}  (3 cndmask per row)
            float a0 = qb0 ? t3 : v0, b0 = qb0 ? t1 : v2;
            float row0 = qb1 ? b0 : a0;
            float a1 = qb0 ? v0 : t1, b1 = qb0 ? v2 : t3;
            float row1 = qb1 ? b1 : a1;
            float a2 = qb0 ? t1 : v2, b2 = qb0 ? t3 : v0;
            float row2 = qb1 ? b2 : a2;
            float a3 = qb0 ? v2 : t3, b3 = qb0 ? v0 : t1;
            float row3 = qb1 ? b3 : a3;
            uint2 hv;
            hv.x = pk_f16(row0, row1);    // rows jD, jD+1
            hv.y = pk_f16(row2, row3);    // rows jD+2, jD+3
            hf = __builtin_bit_cast(half4, hv);
        }
        if (c + 1 < T_LEN / 16) { xc0 = xn0; xc1 = xn1; xc2 = xn2; xc3 = xn3; }
    }

    // ---- FC: lanes {L & 3 == ecol} hold all 16 rows (g x q) exactly once
    float p = hp * fc_w[rme];
    p += __shfl_xor(p, 4, 64);
    p += __shfl_xor(p, 8, 64);
    p += __shfl_xor(p, 16, 64);
    p += __shfl_xor(p, 32, 64);
    if (L < 4) out[blockIdx.x * 4 + L] = p + fc_b[0];
}

} // namespace

extern "C" void kernel_launch(void* const* d_in, const int* in_sizes, int n_in,
                              void* d_out, int out_size, void* d_ws, size_t ws_size,
                              hipStream_t stream) {
    const float* x    = (const float*)d_in[0];
    const float* W_ih = (const float*)d_in[1];
    const float* W_hh = (const float*)d_in[2];
    const float* b_ih = (const float*)d_in[3];
    const float* b_hh = (const float*)d_in[4];
    const float* fc_w = (const float*)d_in[5];
    const float* fc_b = (const float*)d_in[6];
    float* out = (float*)d_out;

    const int B = out_size;               // 8192
    const int blocks = B / 4;             // 4 elements per 1-wave block (4x col dup)
    gru_mfma4d<<<blocks, 64, 0, stream>>>(x, W_ih, W_hh, b_ih, b_hh,
                                          fc_w, fc_b, out);
}

// Round 13
// 106.033 us; speedup vs baseline: 1.1041x; 1.1041x over previous
//
#include <hip/hip_runtime.h>

namespace {

constexpr int T_LEN = 512;
constexpr float LOG2E = 1.4426950408889634f;

typedef _Float16 half4 __attribute__((ext_vector_type(4)));
typedef _Float16 half2v __attribute__((ext_vector_type(2)));
typedef float v4f __attribute__((ext_vector_type(4)));

__device__ __forceinline__ float fexp2(float a) {
#if __has_builtin(__builtin_amdgcn_exp2f)
    return __builtin_amdgcn_exp2f(a);
#else
    return exp2f(a);
#endif
}

__device__ __forceinline__ v4f mfma16h(half4 a, half4 b, v4f c) {
#if __has_builtin(__builtin_amdgcn_mfma_f32_16x16x16f16)
    return __builtin_amdgcn_mfma_f32_16x16x16f16(a, b, c, 0, 0, 0);
#else
    v4f d;
    asm volatile("v_mfma_f32_16x16x16_f16 %0, %1, %2, %3\n\ts_nop 7\n\ts_nop 7"
                 : "=v"(d) : "v"(a), "v"(b), "v"(c));
    return d;
#endif
}

__device__ __forceinline__ unsigned pk_f16(float a, float b) {
#if __has_builtin(__builtin_amdgcn_cvt_pkrtz)
    return __builtin_bit_cast(unsigned, __builtin_amdgcn_cvt_pkrtz(a, b));
#else
    half2v r; r[0] = (_Float16)a; r[1] = (_Float16)b;
    return __builtin_bit_cast(unsigned, r);
#endif
}

// DPP mov, compile-time ctrl. ctrl < 0x100 = QUAD_PERM (explicit lane selects
// within each 4-lane quad -- no direction ambiguity).
// 0xB1 = [1,0,3,2] (swap pairs: lane q <- q^1); 0x4E = [2,3,0,1] (q <- q^2).
template<int CTRL>
__device__ __forceinline__ float dpp_mov_f(float v) {
    return __builtin_bit_cast(float,
        __builtin_amdgcn_mov_dpp(__builtin_bit_cast(int, v), CTRL, 0xF, 0xF, false));
}
template<int CTRL>
__device__ __forceinline__ unsigned dpp_mov_u(unsigned v) {
    return (unsigned)__builtin_amdgcn_mov_dpp((int)v, CTRL, 0xF, 0xF, false);
}

// select d[q] with compile-time vector indices (q = qb1*2 + qb0, per-lane)
__device__ __forceinline__ float sel4(v4f d, bool qb0, bool qb1) {
    float a = qb0 ? d[1] : d[0];
    float b = qb0 ? d[3] : d[2];
    return qb1 ? b : a;
}

// one (row, element) gate evaluation + h update (identical math since R5)
__device__ __forceinline__ float gru_pair(float drp, float dzp, float dnp,
                                          float xt, float wihn, float bihn,
                                          float hp) {
    float Er = fexp2(drp);
    float Ez = fexp2(dzp);
    float pr = 1.0f + Er;
    float pz = 1.0f + Ez;
    float ip = __builtin_amdgcn_rcpf(pr * pz);
    float r  = ip * pz;                  // sigmoid(r-pre)
    float z  = ip * pr;                  // sigmoid(z-pre)
    float xn = __builtin_fmaf(xt, wihn, bihn);
    float v  = __builtin_fmaf(r, dnp, xn);
    float n  = __builtin_fmaf(-2.0f, __builtin_amdgcn_rcpf(1.0f + fexp2(v)), 1.0f);
    return __builtin_fmaf(z, hp - n, n); // (1-z)*n + z*h
}

__global__ __launch_bounds__(64) void gru_q4(
        const float* __restrict__ x,
        const float* __restrict__ W_ih,
        const float* __restrict__ W_hh,
        const float* __restrict__ b_ih,
        const float* __restrict__ b_hh,
        const float* __restrict__ fc_w,
        const float* __restrict__ fc_b,
        float* __restrict__ out) {
    const int L  = threadIdx.x;      // 0..63
    const int e  = L & 15;           // MFMA column
    const int g  = L >> 4;           // row group; D rows jD..jD+3 of col e
    const int jD = g * 4;
    const int elem = e >> 2;         // batch element (4 cols per element)
    const int q    = e & 3;          // duplicate index == which D-reg this lane gates
    const bool qb0 = (q & 1) != 0;
    const bool qb1 = (q & 2) != 0;
    const int be   = blockIdx.x * 4 + elem;
    const int rme  = jD + q;         // the single gate row this lane owns

    const float sR = -LOG2E;         // sigmoid scaling folded into weights
    const float sN = 2.0f * LOG2E;   // tanh scaling

    // ---- A fragments: W_hh rows (gate out m = e; k = jD..jD+3), scaled, f16
    half4 ar_h, az_h, an_h;
#pragma unroll
    for (int i = 0; i < 4; ++i) {
        ar_h[i] = (_Float16)(W_hh[(0  + e) * 16 + jD + i] * sR);
        az_h[i] = (_Float16)(W_hh[(16 + e) * 16 + jD + i] * sR);
        an_h[i] = (_Float16)(W_hh[(32 + e) * 16 + jD + i] * sN);
    }

    // ---- loop-invariant MFMA C-operands: bias vectors (xt folded post-sel)
    v4f c_r, c_z, c_n;
#pragma unroll
    for (int i = 0; i < 4; ++i) {
        int rj = jD + i;
        c_r[i] = (b_ih[rj]      + b_hh[rj])      * sR;
        c_z[i] = (b_ih[16 + rj] + b_hh[16 + rj]) * sR;
        c_n[i] = b_hh[32 + rj] * sN;
    }
    // per-lane scalars for this lane's single gate row
    const float wihr_s = W_ih[rme]      * sR;
    const float wihz_s = W_ih[16 + rme] * sR;
    const float wihn_s = W_ih[32 + rme] * sN;
    const float bihn_s = b_ih[32 + rme] * sN;

    // ---- x timeline (4 duplicate lanes per elem hit identical addresses)
    const float4* xb = (const float4*)(x + (size_t)be * T_LEN);
    float4 xc0 = xb[0], xc1 = xb[1], xc2 = xb[2], xc3 = xb[3];

    float hp = 0.f;                      // this lane's h row (fp32 master)
    uint2 hz; hz.x = 0u; hz.y = 0u;
    half4 hf = __builtin_bit_cast(half4, hz);   // B-frag: rows jD..jD+3 (f16)

#pragma unroll 1
    for (int c = 0; c < T_LEN / 16; ++c) {
        float4 xn0, xn1, xn2, xn3;
        if (c + 1 < T_LEN / 16) {
            xn0 = xb[(c + 1) * 4 + 0];
            xn1 = xb[(c + 1) * 4 + 1];
            xn2 = xb[(c + 1) * 4 + 2];
            xn3 = xb[(c + 1) * 4 + 3];
        }
#pragma unroll
        for (int s = 0; s < 16; ++s) {
            float4 q4 = (s < 4) ? xc0 : (s < 8) ? xc1 : (s < 12) ? xc2 : xc3;
            float xt  = ((s & 3) == 0) ? q4.x : ((s & 3) == 1) ? q4.y
                      : ((s & 3) == 2) ? q4.z : q4.w;

            // matvec on MFMA pipe: ONE f16 MFMA per gate, bias in C
            v4f dr = mfma16h(ar_h, hf, c_r);
            v4f dz = mfma16h(az_h, hf, c_z);
            v4f dn = mfma16h(an_h, hf, c_n);

            // 4-way duplication split: this lane gates only D-reg q (row jD+q)
            float d_r = __builtin_fmaf(xt, wihr_s, sel4(dr, qb0, qb1));
            float d_z = __builtin_fmaf(xt, wihz_s, sel4(dz, qb0, qb1));
            float d_n = sel4(dn, qb0, qb1);
            float hn = gru_pair(d_r, d_z, d_n, xt, wihn_s, bihn_s, hp);
            hp = hn;

            // ---- reassemble B-frag, 7 ops, all within the 4-lane quad:
            // w = partner row jD+(q^1); pack own pair; fetch other pair (q^2).
            float w = dpp_mov_f<0xB1>(hn);            // quad swap-pairs
            float evn = qb0 ? w  : hn;                // row jD+2*(q>>1)
            float odd = qb0 ? hn : w;                 // row jD+2*(q>>1)+1
            unsigned pairu = pk_f16(evn, odd);
            unsigned oth   = dpp_mov_u<0x4E>(pairu);  // quad rotate-by-2
            uint2 hv;
            hv.x = qb1 ? oth   : pairu;               // rows jD, jD+1
            hv.y = qb1 ? pairu : oth;                 // rows jD+2, jD+3
            hf = __builtin_bit_cast(half4, hv);
        }
        if (c + 1 < T_LEN / 16) { xc0 = xn0; xc1 = xn1; xc2 = xn2; xc3 = xn3; }
    }

    // ---- FC: sum over q (xor 1,2) and g (xor 16,32); rep lanes L = 4*elem
    float p = hp * fc_w[rme];
    p += __shfl_xor(p, 1, 64);
    p += __shfl_xor(p, 2, 64);
    p += __shfl_xor(p, 16, 64);
    p += __shfl_xor(p, 32, 64);
    if ((L & 0x33) == 0) out[blockIdx.x * 4 + (L >> 2)] = p + fc_b[0];
}

} // namespace

extern "C" void kernel_launch(void* const* d_in, const int* in_sizes, int n_in,
                              void* d_out, int out_size, void* d_ws, size_t ws_size,
                              hipStream_t stream) {
    const float* x    = (const float*)d_in[0];
    const float* W_ih = (const float*)d_in[1];
    const float* W_hh = (const float*)d_in[2];
    const float* b_ih = (const float*)d_in[3];
    const float* b_hh = (const float*)d_in[4];
    const float* fc_w = (const float*)d_in[5];
    const float* fc_b = (const float*)d_in[6];
    float* out = (float*)d_out;

    const int B = out_size;               // 8192
    const int blocks = B / 4;             // 4 elems/wave (quad-dup) -> 2 waves/SIMD
    gru_q4<<<blocks, 64, 0, stream>>>(x, W_ih, W_hh, b_ih, b_hh,
                                      fc_w, fc_b, out);
}